// Round 1
// baseline (282.920 us; speedup 1.0000x reference)
//
#include <hip/hip_runtime.h>
#include <hip/hip_bf16.h>

#define GAT_ALPHA 0.2f

typedef short bf16x8 __attribute__((ext_vector_type(8)));
typedef float f32x4 __attribute__((ext_vector_type(4)));

__device__ __forceinline__ unsigned f2bf_u(float x) {
  union { float f; unsigned u; } v; v.f = x;
  return (v.u + 0x7fffu + ((v.u >> 16) & 1u)) >> 16;  // RNE to bf16
}
__device__ __forceinline__ unsigned short f2bf(float x) { return (unsigned short)f2bf_u(x); }

// ---------------- kernel 0: W (512x256 f32) -> WT bf16 (256x512) ----------
__global__ void k_wt(const float* __restrict__ W, unsigned short* __restrict__ WT) {
  int kb = blockIdx.x * 8;       // 64 blocks
  int f = threadIdx.x;           // 256 threads = one f each
  bf16x8 o;
#pragma unroll
  for (int i = 0; i < 8; ++i) o[i] = (short)f2bf(W[(kb + i) * 256 + f]);  // coalesced reads
  *reinterpret_cast<bf16x8*>(WT + f * 512 + kb) = o;
}

// ---------------- kernel 1: WhT = (h@W)^T in bf16, + exp(f1/f2) arrays ----
// D[m=f][n=node] = sum_k WT[f][k] * h[n][k].  Block: 256 f x 64 nodes, 8 waves.
__global__ __launch_bounds__(512, 2) void k_gemm1(
    const float* __restrict__ h, const unsigned short* __restrict__ WT,
    const float* __restrict__ avec,
    unsigned short* __restrict__ WhT,
    float* __restrict__ E1p, float* __restrict__ E1n,
    float* __restrict__ E2p, float* __restrict__ E2n)
{
  const int bx = blockIdx.x;               // 256 blocks = 8 batches x 32 node-groups
  const int b = bx & 7, ng = bx >> 3;
  const int n0 = ng * 64;
  const int t = threadIdx.x;
  const int lane = t & 63, w = t >> 6;
  const int mtg = w >> 1, ntp = w & 1;     // wave: 4 m-tiles (64 f) x 2 n-tiles (32 nodes)
  const int l15 = lane & 15, q = lane >> 4;

  __shared__ float f1acc[64], f2acc[64];
  if (t < 64) { f1acc[t] = 0.f; f2acc[t] = 0.f; }

  f32x4 acc[4][2];
#pragma unroll
  for (int i = 0; i < 4; ++i)
#pragma unroll
    for (int j = 0; j < 2; ++j) acc[i][j] = (f32x4){0.f, 0.f, 0.f, 0.f};

  const size_t hrow0 = ((size_t)(b * 2048 + n0 + ntp * 32 + l15)) * 512;

#pragma unroll 2
  for (int k0 = 0; k0 < 512; k0 += 32) {
    bf16x8 af[4];
#pragma unroll
    for (int mt = 0; mt < 4; ++mt) {
      int fr = mtg * 64 + mt * 16 + l15;
      af[mt] = *reinterpret_cast<const bf16x8*>(WT + fr * 512 + k0 + q * 8);
    }
    bf16x8 bfr[2];
#pragma unroll
    for (int nt = 0; nt < 2; ++nt) {
      const float* hp = h + hrow0 + (size_t)nt * (16 * 512) + k0 + q * 8;
      float4 x0 = *reinterpret_cast<const float4*>(hp);
      float4 x1 = *reinterpret_cast<const float4*>(hp + 4);
      bf16x8 bb;
      bb[0] = (short)f2bf(x0.x); bb[1] = (short)f2bf(x0.y);
      bb[2] = (short)f2bf(x0.z); bb[3] = (short)f2bf(x0.w);
      bb[4] = (short)f2bf(x1.x); bb[5] = (short)f2bf(x1.y);
      bb[6] = (short)f2bf(x1.z); bb[7] = (short)f2bf(x1.w);
      bfr[nt] = bb;
    }
#pragma unroll
    for (int mt = 0; mt < 4; ++mt)
#pragma unroll
      for (int nt = 0; nt < 2; ++nt)
        acc[mt][nt] = __builtin_amdgcn_mfma_f32_16x16x32_bf16(af[mt], bfr[nt], acc[mt][nt], 0, 0, 0);
  }

  // Epilogue: C row = f-offset (q*4+r), col = node (l15). Store WhT + f1/f2 partials.
  float s1[2] = {0.f, 0.f}, s2[2] = {0.f, 0.f};
#pragma unroll
  for (int mt = 0; mt < 4; ++mt) {
#pragma unroll
    for (int nt = 0; nt < 2; ++nt) {
      int n = n0 + ntp * 32 + nt * 16 + l15;
#pragma unroll
      for (int r = 0; r < 4; ++r) {
        int f = mtg * 64 + mt * 16 + q * 4 + r;
        float v = acc[mt][nt][r];
        WhT[(size_t)(b * 256 + f) * 2048 + n] = f2bf(v);
        s1[nt] += v * avec[f];
        s2[nt] += v * avec[256 + f];
      }
    }
  }
  __syncthreads();  // f1acc/f2acc init visible before atomics
#pragma unroll
  for (int nt = 0; nt < 2; ++nt) {
    float a1 = s1[nt], a2 = s2[nt];
    a1 += __shfl_xor(a1, 16); a1 += __shfl_xor(a1, 32);
    a2 += __shfl_xor(a2, 16); a2 += __shfl_xor(a2, 32);
    if (q == 0) {
      atomicAdd(&f1acc[ntp * 32 + nt * 16 + l15], a1);
      atomicAdd(&f2acc[ntp * 32 + nt * 16 + l15], a2);
    }
  }
  __syncthreads();
  if (t < 64) {
    int n = b * 2048 + n0 + t;
    float f1 = f1acc[t], f2 = f2acc[t];
    E1p[n] = __expf(f1);
    E1n[n] = __expf(GAT_ALPHA * f1);
    E2p[n] = __expf(f2);
    E2n[n] = __expf(GAT_ALPHA * f2);
  }
}

// ---------------- kernel 2: masked-softmax(P) @ Wh, fused, adj streamed once
// Block: 64 rows x 256 f, batch = blockIdx&7 (XCD-pinned WhT reuse in L2).
// p(i,j) = adj ? max(e^f1*e^f2, e^{.2f1}*e^{.2f2}) : 0  (== exp(leaky(f1+f2)))
__global__ __launch_bounds__(512, 2) void k_gat(
    const int* __restrict__ adj, const unsigned short* __restrict__ WhT,
    const float* __restrict__ E1p, const float* __restrict__ E1n,
    const float* __restrict__ E2p, const float* __restrict__ E2n,
    float* __restrict__ out)
{
  const int bx = blockIdx.x;               // 256 blocks = 8 batches x 32 row-groups
  const int b = bx & 7, ig = bx >> 3;
  const int i0 = ig * 64;
  const int t = threadIdx.x;
  const int lane = t & 63, w = t >> 6;
  const int l15 = lane & 15, q = lane >> 4;
  const int crow = t >> 5;                 // construction: rows crow+16p, p=0..3
  const int ccol = (t & 31) * 4;           // 4 consecutive j per pass

  __shared__ unsigned short Pb[2][64][136];  // padded stride: 272B, 16B-aligned, uniform banks
  __shared__ float den_l[64];

  float e1p[4], e1n[4];
#pragma unroll
  for (int p = 0; p < 4; ++p) {
    int r = b * 2048 + i0 + crow + 16 * p;
    e1p[p] = E1p[r]; e1n[p] = E1n[r];
  }
  float den[4] = {0.f, 0.f, 0.f, 0.f};

  const size_t adjbase = ((size_t)(b * 2048 + i0 + crow)) * 2048 + ccol;
  const int e2base = b * 2048 + ccol;

  f32x4 acc[4][2];
#pragma unroll
  for (int i = 0; i < 4; ++i)
#pragma unroll
    for (int j = 0; j < 2; ++j) acc[i][j] = (f32x4){0.f, 0.f, 0.f, 0.f};

  // ---- prologue: load + construct chunk 0 into Pb[0]
  int4 av[4]; float4 e2pv, e2nv;
#pragma unroll
  for (int p = 0; p < 4; ++p)
    av[p] = *reinterpret_cast<const int4*>(adj + adjbase + (size_t)(16 * p) * 2048);
  e2pv = *reinterpret_cast<const float4*>(E2p + e2base);
  e2nv = *reinterpret_cast<const float4*>(E2n + e2base);
  {
    unsigned short* wb = &Pb[0][0][0];
#pragma unroll
    for (int p = 0; p < 4; ++p) {
      float p0 = fmaxf(e1p[p] * e2pv.x, e1n[p] * e2nv.x); p0 = av[p].x ? p0 : 0.f;
      float p1 = fmaxf(e1p[p] * e2pv.y, e1n[p] * e2nv.y); p1 = av[p].y ? p1 : 0.f;
      float p2 = fmaxf(e1p[p] * e2pv.z, e1n[p] * e2nv.z); p2 = av[p].z ? p2 : 0.f;
      float p3 = fmaxf(e1p[p] * e2pv.w, e1n[p] * e2nv.w); p3 = av[p].w ? p3 : 0.f;
      den[p] += (p0 + p1) + (p2 + p3);
      uint2 pk;
      pk.x = f2bf_u(p0) | (f2bf_u(p1) << 16);
      pk.y = f2bf_u(p2) | (f2bf_u(p3) << 16);
      *reinterpret_cast<uint2*>(wb + (crow + 16 * p) * 136 + ccol) = pk;
    }
  }

  for (int c = 0; c < 16; ++c) {
    __syncthreads();   // Pb[c&1] ready; prev readers of Pb[(c+1)&1] are done
    // prefetch chunk c+1 (in flight during MFMA section)
    int4 nav[4]; float4 ne2p, ne2n;
    if (c < 15) {
      int j0 = (c + 1) * 128;
#pragma unroll
      for (int p = 0; p < 4; ++p)
        nav[p] = *reinterpret_cast<const int4*>(adj + adjbase + (size_t)(16 * p) * 2048 + j0);
      ne2p = *reinterpret_cast<const float4*>(E2p + e2base + j0);
      ne2n = *reinterpret_cast<const float4*>(E2n + e2base + j0);
    }
    // MFMA on chunk c: A from LDS, B direct from L2-resident WhT
    const unsigned short* pbuf = &Pb[c & 1][0][0];
#pragma unroll
    for (int ks = 0; ks < 4; ++ks) {
      bf16x8 afr[4];
#pragma unroll
      for (int rt = 0; rt < 4; ++rt)
        afr[rt] = *reinterpret_cast<const bf16x8*>(pbuf + (rt * 16 + l15) * 136 + ks * 32 + q * 8);
      bf16x8 bfr[2];
#pragma unroll
      for (int ct = 0; ct < 2; ++ct) {
        int f = w * 32 + ct * 16 + l15;
        bfr[ct] = *reinterpret_cast<const bf16x8*>(
            WhT + (size_t)(b * 256 + f) * 2048 + c * 128 + ks * 32 + q * 8);
      }
#pragma unroll
      for (int rt = 0; rt < 4; ++rt)
#pragma unroll
        for (int ct = 0; ct < 2; ++ct)
          acc[rt][ct] = __builtin_amdgcn_mfma_f32_16x16x32_bf16(afr[rt], bfr[ct], acc[rt][ct], 0, 0, 0);
    }
    // construct chunk c+1 into the other buffer (VALU overlaps MFMA pipe)
    if (c < 15) {
      unsigned short* wb = &Pb[(c + 1) & 1][0][0];
#pragma unroll
      for (int p = 0; p < 4; ++p) {
        float p0 = fmaxf(e1p[p] * ne2p.x, e1n[p] * ne2n.x); p0 = nav[p].x ? p0 : 0.f;
        float p1 = fmaxf(e1p[p] * ne2p.y, e1n[p] * ne2n.y); p1 = nav[p].y ? p1 : 0.f;
        float p2 = fmaxf(e1p[p] * ne2p.z, e1n[p] * ne2n.z); p2 = nav[p].z ? p2 : 0.f;
        float p3 = fmaxf(e1p[p] * ne2p.w, e1n[p] * ne2n.w); p3 = nav[p].w ? p3 : 0.f;
        den[p] += (p0 + p1) + (p2 + p3);
        uint2 pk;
        pk.x = f2bf_u(p0) | (f2bf_u(p1) << 16);
        pk.y = f2bf_u(p2) | (f2bf_u(p3) << 16);
        *reinterpret_cast<uint2*>(wb + (crow + 16 * p) * 136 + ccol) = pk;
      }
    }
  }

  // denominator: reduce over the 16 col-threads (lanes sharing t>>5)
#pragma unroll
  for (int p = 0; p < 4; ++p) {
    float s = den[p];
    s += __shfl_xor(s, 1); s += __shfl_xor(s, 2); s += __shfl_xor(s, 4);
    s += __shfl_xor(s, 8); s += __shfl_xor(s, 16);
    if ((lane & 31) == 0) den_l[(t >> 5) + 16 * p] = s;
  }
  __syncthreads();

  // epilogue: out = elu(acc/den), C row = rt*16+q*4+r, col f = w*32+ct*16+l15
#pragma unroll
  for (int rt = 0; rt < 4; ++rt) {
#pragma unroll
    for (int r = 0; r < 4; ++r) {
      int row = rt * 16 + q * 4 + r;
      float dinv = 1.0f / den_l[row];
      size_t obase = ((size_t)(b * 2048 + i0 + row)) * 256;
#pragma unroll
      for (int ct = 0; ct < 2; ++ct) {
        int f = w * 32 + ct * 16 + l15;
        float v = acc[rt][ct][r] * dinv;
        v = v > 0.f ? v : (__expf(v) - 1.f);
        out[obase + f] = v;
      }
    }
  }
}

extern "C" void kernel_launch(void* const* d_in, const int* in_sizes, int n_in,
                              void* d_out, int out_size, void* d_ws, size_t ws_size,
                              hipStream_t stream) {
  const float* h   = (const float*)d_in[0];   // [8,2048,512] f32
  const int*   adj = (const int*)d_in[1];     // [8,2048,2048] i32
  const float* W   = (const float*)d_in[2];   // [512,256] f32
  const float* a   = (const float*)d_in[3];   // [512,1] f32
  float* out = (float*)d_out;                 // [8,2048,256] f32

  char* ws = (char*)d_ws;
  unsigned short* WhT = (unsigned short*)ws;                       // 8 MB  [8][256][2048] bf16
  unsigned short* WT  = (unsigned short*)(ws + 8388608);           // 256 KB [256][512] bf16
  float* E1p = (float*)(ws + 8388608 + 262144);                    // 64 KB each
  float* E1n = E1p + 16384;
  float* E2p = E1n + 16384;
  float* E2n = E2p + 16384;

  k_wt<<<dim3(64), dim3(256), 0, stream>>>(W, WT);
  k_gemm1<<<dim3(256), dim3(512), 0, stream>>>(h, WT, a, WhT, E1p, E1n, E2p, E2n);
  k_gat<<<dim3(256), dim3(512), 0, stream>>>(adj, WhT, E1p, E1n, E2p, E2n, out);
}